// Round 14
// baseline (225.401 us; speedup 1.0000x reference)
//
#include <hip/hip_runtime.h>
#include <cstdint>

#define T_TOK 512
#define H_DIM 2048
#define I_DIM 1408
#define N_EXP 16

typedef __attribute__((ext_vector_type(8))) _Float16 f16x8;
typedef __attribute__((ext_vector_type(4))) float f32x4;

__device__ __forceinline__ void gload_lds16(const void* g, void* l) {
  auto gp = (const __attribute__((address_space(1))) unsigned int*)(unsigned long long)g;
  unsigned int loff = (unsigned int)(unsigned long long)l;
  auto lp = (__attribute__((address_space(3))) unsigned int*)loff;
  __builtin_amdgcn_global_load_lds(gp, lp, 16, 0, 0);
}

__device__ __forceinline__ f16x8 cvt8(f32x4 a, f32x4 b) {
  f16x8 r;
  r[0] = (_Float16)a[0]; r[1] = (_Float16)a[1]; r[2] = (_Float16)a[2]; r[3] = (_Float16)a[3];
  r[4] = (_Float16)b[0]; r[5] = (_Float16)b[1]; r[6] = (_Float16)b[2]; r[7] = (_Float16)b[3];
  return r;
}

// ---------------- kernel 1: routing + x -> fp16 ----------------
__global__ __launch_bounds__(256) void route_kernel(
    const float* __restrict__ x, const float* __restrict__ gw,
    const float* __restrict__ bias, float* __restrict__ coef,
    _Float16* __restrict__ xb) {
  const int t = blockIdx.x;
  const int tid = threadIdx.x;
  const float* xt = x + (size_t)t * H_DIM;
  _Float16* xbt = xb + (size_t)t * H_DIM;

  float part[N_EXP];
#pragma unroll
  for (int e = 0; e < N_EXP; ++e) part[e] = 0.f;
  for (int j = tid; j < H_DIM; j += 256) {
    float xv = xt[j];
    xbt[j] = (_Float16)xv;
#pragma unroll
    for (int e = 0; e < N_EXP; ++e) part[e] += xv * gw[e * H_DIM + j];
  }
#pragma unroll
  for (int e = 0; e < N_EXP; ++e) {
#pragma unroll
    for (int off = 32; off > 0; off >>= 1) part[e] += __shfl_down(part[e], off);
  }
  __shared__ float red[4][N_EXP];
  const int lane = tid & 63, w = tid >> 6;
  if (lane == 0) {
#pragma unroll
    for (int e = 0; e < N_EXP; ++e) red[w][e] = part[e];
  }
  __syncthreads();
  if (tid == 0) {
    float s[16], sf[16];
    for (int e = 0; e < 16; ++e) {
      float lg = red[0][e] + red[1][e] + red[2][e] + red[3][e];
      s[e] = 1.f / (1.f + expf(-lg));
      sf[e] = s[e] + bias[e];
    }
    float gsc[4];
    for (int g = 0; g < 4; ++g) {
      float m1 = -1e30f, m2 = -1e30f;
      for (int j = 0; j < 4; ++j) {
        float v = sf[g * 4 + j];
        if (v > m1) { m2 = m1; m1 = v; }
        else if (v > m2) { m2 = v; }
      }
      gsc[g] = m1 + m2;
    }
    int g1 = 0;
    for (int g = 1; g < 4; ++g) if (gsc[g] > gsc[g1]) g1 = g;
    int g2 = -1;
    for (int g = 0; g < 4; ++g) {
      if (g == g1) continue;
      if (g2 < 0 || gsc[g] > gsc[g2]) g2 = g;
    }
    bool gok[4];
    for (int g = 0; g < 4; ++g) gok[g] = (g == g1) || (g == g2);
    bool sel[16];
    for (int e = 0; e < 16; ++e) sel[e] = false;
    float wsum = 0.f;
    for (int k = 0; k < 6; ++k) {
      int best = -1; float bv = 0.f;
      for (int e2 = 0; e2 < 16; ++e2) {
        if (!gok[e2 >> 2] || sel[e2]) continue;
        if (best < 0 || sf[e2] > bv) { bv = sf[e2]; best = e2; }
      }
      sel[best] = true;
      wsum += s[best];
    }
    float inv = 2.5f / wsum;
    for (int e = 0; e < 16; ++e) coef[t * N_EXP + e] = sel[e] ? s[e] * inv : 0.f;
  }
}

// ---------------- kernel 2: per-expert token lists ----------------
__global__ __launch_bounds__(512) void build_lists_kernel(
    const float* __restrict__ coef, int* __restrict__ counts,
    int* __restrict__ lists) {
  const int e = blockIdx.x;
  const int t = threadIdx.x;
  const bool flag = coef[t * N_EXP + e] != 0.f;
  const unsigned long long m = __ballot(flag);
  const int lane = t & 63, w = t >> 6;
  __shared__ int wcnt[8], woff[8];
  if (lane == 0) wcnt[w] = __popcll(m);
  __syncthreads();
  if (t == 0) {
    int a = 0;
    for (int i = 0; i < 8; ++i) { woff[i] = a; a += wcnt[i]; }
    counts[e] = a;
  }
  __syncthreads();
  if (flag) {
    int pos = woff[w] + __popcll(m & ((1ull << lane) - 1ull));
    lists[e * T_TOK + pos] = t;
  }
}

// ---------------- kernel 3: gate+up GEMM, BK=32, 64 KB LDS (2 blocks/CU) ----
// BM=256, BN=64, BK=32, 256 thr / 4 waves, wave tile 64 rows x 64 cols (x2).
// All staging pure-async gload_lds (8 instr/wave/iter):
//   A frag-linear f16 [2][16KB]; Bg/Bu fp32 chunk-swizzled [2][8KB] each.
// Grid plain (22,2,16); y=1 live for ne<=256 -> B read once per (strip,e).
__global__ __launch_bounds__(256, 2) void gate_up_kernel(
    const _Float16* __restrict__ xb, const float* __restrict__ wg,
    const float* __restrict__ wu, const int* __restrict__ counts,
    const int* __restrict__ lists, _Float16* __restrict__ hbuf) {
  extern __shared__ char lds[];
  // A [2][16384] @0 ; Bg [2][8192] @32768 ; Bu [2][8192] @49152
  const int e = blockIdx.z;
  const int ne = counts[e];
  const int row0 = blockIdx.y * 256;
  if (row0 >= ne) return;
  const int col0 = blockIdx.x * 64;
  const int tid = threadIdx.x;
  const int lane = tid & 63;
  const int w = tid >> 6;        // 0..3, owns rows w*64..w*64+63

  // ---- A sources: wave w stages its own 4 m-blocks (frag-linear)
  // lane: row (l&15), k-chunk (l>>4) of 4x16B (BK=32 f16)
  const int* lst = lists + e * T_TOK;
  const _Float16* asrc[4];
#pragma unroll
  for (int i = 0; i < 4; ++i) {
    int r = row0 + (4 * w + i) * 16 + (lane & 15);
    int tok = lst[min(r, ne - 1)];
    asrc[i] = xb + (size_t)tok * H_DIM + (lane >> 4) * 8;
  }
  // ---- B sources: 2 instr/wave/matrix; instr i: W-row (w*2+i)*8+(l>>3),
  // 16B chunk (l&7) source-pre-swizzled (BK=32 fp32 = 8 chunks)
  const float* bgs[2];
  const float* bus[2];
#pragma unroll
  for (int i = 0; i < 2; ++i) {
    int tr = (w * 2 + i) * 8 + (lane >> 3);
    int ls = (lane & 7) ^ (tr & 7);
    bgs[i] = wg + ((size_t)e * I_DIM + col0 + tr) * H_DIM + ls * 4;
    bus[i] = wu + ((size_t)e * I_DIM + col0 + tr) * H_DIM + ls * 4;
  }

  f32x4 accg[4][4], accu[4][4];
  const f32x4 zz = {0.f, 0.f, 0.f, 0.f};
#pragma unroll
  for (int m = 0; m < 4; ++m)
#pragma unroll
    for (int n = 0; n < 4; ++n) { accg[m][n] = zz; accu[m][n] = zz; }

  auto stage = [&](int kt, int buf) {   // 8 pure-async instr per wave
    const int k0 = kt * 32;
#pragma unroll
    for (int i = 0; i < 4; ++i)
      gload_lds16(asrc[i] + k0, lds + buf * 16384 + (4 * w + i) * 1024);
#pragma unroll
    for (int i = 0; i < 2; ++i) {
      gload_lds16(bgs[i] + k0, lds + 32768 + buf * 8192 + (w * 2 + i) * 1024);
      gload_lds16(bus[i] + k0, lds + 49152 + buf * 8192 + (w * 2 + i) * 1024);
    }
  };

  auto comp = [&](int buf) {
    const char* Ab = lds + buf * 16384;
    const char* Gb = lds + 32768 + buf * 8192;
    const char* Ub = lds + 49152 + buf * 8192;
    f16x8 afr[4];
#pragma unroll
    for (int m = 0; m < 4; ++m)
      afr[m] = *(const f16x8*)(Ab + (w * 4 + m) * 1024 + lane * 16);
    const int s0 = (lane >> 4) * 2;
#pragma unroll
    for (int n = 0; n < 4; ++n) {
      int c = n * 16 + (lane & 15);
      int p0 = s0 ^ (c & 7);
      int p1 = (s0 + 1) ^ (c & 7);
      f16x8 bg = cvt8(*(const f32x4*)(Gb + c * 128 + p0 * 16),
                      *(const f32x4*)(Gb + c * 128 + p1 * 16));
      f16x8 bu = cvt8(*(const f32x4*)(Ub + c * 128 + p0 * 16),
                      *(const f32x4*)(Ub + c * 128 + p1 * 16));
#pragma unroll
      for (int m = 0; m < 4; ++m) {
        accg[m][n] = __builtin_amdgcn_mfma_f32_16x16x32_f16(afr[m], bg, accg[m][n], 0, 0, 0);
        accu[m][n] = __builtin_amdgcn_mfma_f32_16x16x32_f16(afr[m], bu, accu[m][n], 0, 0, 0);
      }
    }
  };

  const int NK = H_DIM / 32;   // 64
  stage(0, 0);
  for (int kt = 0; kt < NK; ++kt) {
    __syncthreads();
    if (kt + 1 < NK) stage(kt + 1, (kt + 1) & 1);
    comp(kt & 1);
  }

  // epilogue: silu(g)*u -> fp16 h
  _Float16* hb = hbuf + (size_t)e * T_TOK * I_DIM;
#pragma unroll
  for (int m = 0; m < 4; ++m) {
#pragma unroll
    for (int j = 0; j < 4; ++j) {
      int r = row0 + w * 64 + m * 16 + (lane >> 4) * 4 + j;
      if (r < ne) {
#pragma unroll
        for (int n = 0; n < 4; ++n) {
          int cc = col0 + n * 16 + (lane & 15);
          float g = accg[m][n][j];
          float u = accu[m][n][j];
          float hv = (g / (1.f + __expf(-g))) * u;
          hb[(size_t)r * I_DIM + cc] = (_Float16)hv;
        }
      }
    }
  }
}

// ---------------- kernel 4: down GEMM, BK=64 all-async + scatter-add --------
// (unchanged from round 9 — L3-resident wd, measured ~45 B/cy/CU)
__global__ __launch_bounds__(512) void down_kernel(
    const _Float16* __restrict__ hbuf, const float* __restrict__ wd,
    const int* __restrict__ counts, const int* __restrict__ lists,
    const float* __restrict__ coef, float* __restrict__ out) {
  extern __shared__ char lds[];
  // offsets: A [2][32768] @0 ; B [2][16384] @65536
  const int e = blockIdx.z;
  const int ne = counts[e];
  const int row0 = blockIdx.y * 256;
  if (row0 >= ne) return;
  const int col0 = blockIdx.x * 64;
  const int tid = threadIdx.x;
  const int lane = tid & 63;
  const int w = tid >> 6;
  const int wr = w >> 1, wc = w & 1;

  const _Float16* hb = hbuf + (size_t)e * T_TOK * I_DIM;
  const _Float16* asrc[4];
#pragma unroll
  for (int i = 0; i < 4; ++i) {
    int tr = (w * 4 + i) * 8 + (lane >> 3);
    int lchunk = (lane & 7) ^ (tr & 7);
    asrc[i] = hb + (size_t)(row0 + tr) * I_DIM + lchunk * 8;
  }
  const float* bds[2];
#pragma unroll
  for (int i = 0; i < 2; ++i) {
    int tr = (w * 2 + i) * 4 + (lane >> 4);
    int ls = (lane & 15) ^ ((tr & 7) << 1);
    bds[i] = wd + ((size_t)e * H_DIM + col0 + tr) * I_DIM + ls * 4;
  }

  f32x4 acc[4][2];
  const f32x4 zz = {0.f, 0.f, 0.f, 0.f};
#pragma unroll
  for (int m = 0; m < 4; ++m)
#pragma unroll
    for (int n = 0; n < 2; ++n) acc[m][n] = zz;

  auto stage = [&](int kt, int buf) {
    const int k0 = kt * 64;
#pragma unroll
    for (int i = 0; i < 4; ++i)
      gload_lds16(asrc[i] + k0, lds + buf * 32768 + (w * 4 + i) * 1024);
#pragma unroll
    for (int i = 0; i < 2; ++i)
      gload_lds16(bds[i] + k0, lds + 65536 + buf * 16384 + (w * 2 + i) * 1024);
  };

  auto comp = [&](int buf) {
    const char* Ab = lds + buf * 32768;
    const char* Bb = lds + 65536 + buf * 16384;
#pragma unroll
    for (int kk = 0; kk < 2; ++kk) {
      f16x8 afr[4], bf[2];
#pragma unroll
      for (int m = 0; m < 4; ++m) {
        int row = wr * 64 + m * 16 + (lane & 15);
        int pch = (kk * 4 + (lane >> 4)) ^ (row & 7);
        afr[m] = *(const f16x8*)(Ab + row * 128 + pch * 16);
      }
#pragma unroll
      for (int n = 0; n < 2; ++n) {
        int c = wc * 32 + n * 16 + (lane & 15);
        int s0 = kk * 8 + (lane >> 4) * 2;
        int p0 = s0 ^ ((c & 7) << 1);
        int p1 = (s0 + 1) ^ ((c & 7) << 1);
        bf[n] = cvt8(*(const f32x4*)(Bb + c * 256 + p0 * 16),
                     *(const f32x4*)(Bb + c * 256 + p1 * 16));
      }
#pragma unroll
      for (int m = 0; m < 4; ++m)
#pragma unroll
        for (int n = 0; n < 2; ++n)
          acc[m][n] = __builtin_amdgcn_mfma_f32_16x16x32_f16(afr[m], bf[n], acc[m][n], 0, 0, 0);
    }
  };

  const int NK = I_DIM / 64;   // 22
  stage(0, 0);
  for (int kt = 0; kt < NK; ++kt) {
    __syncthreads();
    if (kt + 1 < NK) stage(kt + 1, (kt + 1) & 1);
    comp(kt & 1);
  }

#pragma unroll
  for (int m = 0; m < 4; ++m) {
#pragma unroll
    for (int j = 0; j < 4; ++j) {
      int r = row0 + wr * 64 + m * 16 + (lane >> 4) * 4 + j;
      if (r < ne) {
        int tok = lists[e * T_TOK + r];
        float c = coef[tok * N_EXP + e];
#pragma unroll
        for (int n = 0; n < 2; ++n) {
          int cc = col0 + wc * 32 + n * 16 + (lane & 15);
          atomicAdd(&out[(size_t)tok * H_DIM + cc], acc[m][n][j] * c);
        }
      }
    }
  }
}

// ---------------- launch ----------------
extern "C" void kernel_launch(void* const* d_in, const int* in_sizes, int n_in,
                              void* d_out, int out_size, void* d_ws, size_t ws_size,
                              hipStream_t stream) {
  const float* x  = (const float*)d_in[0];
  const float* gw = (const float*)d_in[1];
  const float* cb = (const float*)d_in[2];
  const float* wg = (const float*)d_in[3];
  const float* wu = (const float*)d_in[4];
  const float* wd = (const float*)d_in[5];
  float* out = (float*)d_out;
  char* ws = (char*)d_ws;

  float* coef   = (float*)(ws);                    // 512*16*4 = 32768
  int*   counts = (int*)(ws + 32768);              // 64 B
  int*   lists  = (int*)(ws + 33024);              // 16*512*4 = 32768
  _Float16* xb  = (_Float16*)(ws + 66048);         // 512*2048*2 = 2 MiB
  _Float16* hbuf= (_Float16*)(ws + 66048 + 2097152 + 256); // 16*512*1408*2 = 23 MiB

  hipFuncSetAttribute((const void*)gate_up_kernel,
                      hipFuncAttributeMaxDynamicSharedMemorySize, 65536);
  hipFuncSetAttribute((const void*)down_kernel,
                      hipFuncAttributeMaxDynamicSharedMemorySize, 98304);

  hipMemsetAsync(d_out, 0, (size_t)out_size * sizeof(float), stream);

  route_kernel<<<T_TOK, 256, 0, stream>>>(x, gw, cb, coef, xb);
  build_lists_kernel<<<N_EXP, 512, 0, stream>>>(coef, counts, lists);
  gate_up_kernel<<<dim3(I_DIM / 64, 2, N_EXP), 256, 65536, stream>>>(xb, wg, wu, counts, lists, hbuf);
  down_kernel<<<dim3(H_DIM / 64, 2, N_EXP), 512, 98304, stream>>>(hbuf, wd, counts, lists, coef, out);
}

// Round 15
// 207.731 us; speedup vs baseline: 1.0851x; 1.0851x over previous
//
#include <hip/hip_runtime.h>
#include <cstdint>

#define T_TOK 512
#define H_DIM 2048
#define I_DIM 1408
#define N_EXP 16

typedef __attribute__((ext_vector_type(8))) _Float16 f16x8;
typedef __attribute__((ext_vector_type(4))) float f32x4;

__device__ __forceinline__ void gload_lds16(const void* g, void* l) {
  auto gp = (const __attribute__((address_space(1))) unsigned int*)(unsigned long long)g;
  unsigned int loff = (unsigned int)(unsigned long long)l;
  auto lp = (__attribute__((address_space(3))) unsigned int*)loff;
  __builtin_amdgcn_global_load_lds(gp, lp, 16, 0, 0);
}

__device__ __forceinline__ f16x8 cvt8(f32x4 a, f32x4 b) {
  f16x8 r;
  r[0] = (_Float16)a[0]; r[1] = (_Float16)a[1]; r[2] = (_Float16)a[2]; r[3] = (_Float16)a[3];
  r[4] = (_Float16)b[0]; r[5] = (_Float16)b[1]; r[6] = (_Float16)b[2]; r[7] = (_Float16)b[3];
  return r;
}

// ---------------- kernel 1: routing + x -> fp16 ----------------
__global__ __launch_bounds__(256) void route_kernel(
    const float* __restrict__ x, const float* __restrict__ gw,
    const float* __restrict__ bias, float* __restrict__ coef,
    _Float16* __restrict__ xb) {
  const int t = blockIdx.x;
  const int tid = threadIdx.x;
  const float* xt = x + (size_t)t * H_DIM;
  _Float16* xbt = xb + (size_t)t * H_DIM;

  float part[N_EXP];
#pragma unroll
  for (int e = 0; e < N_EXP; ++e) part[e] = 0.f;
  for (int j = tid; j < H_DIM; j += 256) {
    float xv = xt[j];
    xbt[j] = (_Float16)xv;
#pragma unroll
    for (int e = 0; e < N_EXP; ++e) part[e] += xv * gw[e * H_DIM + j];
  }
#pragma unroll
  for (int e = 0; e < N_EXP; ++e) {
#pragma unroll
    for (int off = 32; off > 0; off >>= 1) part[e] += __shfl_down(part[e], off);
  }
  __shared__ float red[4][N_EXP];
  const int lane = tid & 63, w = tid >> 6;
  if (lane == 0) {
#pragma unroll
    for (int e = 0; e < N_EXP; ++e) red[w][e] = part[e];
  }
  __syncthreads();
  if (tid == 0) {
    float s[16], sf[16];
    for (int e = 0; e < 16; ++e) {
      float lg = red[0][e] + red[1][e] + red[2][e] + red[3][e];
      s[e] = 1.f / (1.f + expf(-lg));
      sf[e] = s[e] + bias[e];
    }
    float gsc[4];
    for (int g = 0; g < 4; ++g) {
      float m1 = -1e30f, m2 = -1e30f;
      for (int j = 0; j < 4; ++j) {
        float v = sf[g * 4 + j];
        if (v > m1) { m2 = m1; m1 = v; }
        else if (v > m2) { m2 = v; }
      }
      gsc[g] = m1 + m2;
    }
    int g1 = 0;
    for (int g = 1; g < 4; ++g) if (gsc[g] > gsc[g1]) g1 = g;
    int g2 = -1;
    for (int g = 0; g < 4; ++g) {
      if (g == g1) continue;
      if (g2 < 0 || gsc[g] > gsc[g2]) g2 = g;
    }
    bool gok[4];
    for (int g = 0; g < 4; ++g) gok[g] = (g == g1) || (g == g2);
    bool sel[16];
    for (int e = 0; e < 16; ++e) sel[e] = false;
    float wsum = 0.f;
    for (int k = 0; k < 6; ++k) {
      int best = -1; float bv = 0.f;
      for (int e2 = 0; e2 < 16; ++e2) {
        if (!gok[e2 >> 2] || sel[e2]) continue;
        if (best < 0 || sf[e2] > bv) { bv = sf[e2]; best = e2; }
      }
      sel[best] = true;
      wsum += s[best];
    }
    float inv = 2.5f / wsum;
    for (int e = 0; e < 16; ++e) coef[t * N_EXP + e] = sel[e] ? s[e] * inv : 0.f;
  }
}

// ---------------- kernel 2: per-expert token lists ----------------
__global__ __launch_bounds__(512) void build_lists_kernel(
    const float* __restrict__ coef, int* __restrict__ counts,
    int* __restrict__ lists) {
  const int e = blockIdx.x;
  const int t = threadIdx.x;
  const bool flag = coef[t * N_EXP + e] != 0.f;
  const unsigned long long m = __ballot(flag);
  const int lane = t & 63, w = t >> 6;
  __shared__ int wcnt[8], woff[8];
  if (lane == 0) wcnt[w] = __popcll(m);
  __syncthreads();
  if (t == 0) {
    int a = 0;
    for (int i = 0; i < 8; ++i) { woff[i] = a; a += wcnt[i]; }
    counts[e] = a;
  }
  __syncthreads();
  if (flag) {
    int pos = woff[w] + __popcll(m & ((1ull << lane) - 1ull));
    lists[e * T_TOK + pos] = t;
  }
}

// ---------------- kernel 3: gate+up GEMM, BN=128 + counted-vmcnt pipeline ---
// BM=256, BN=128, BK=32, 512 thr / 8 waves (4r x 2c), wave tile 64x64 (x2).
// LDS 96 KB dynamic: A frag-linear f16 [2][16KB]; Bg/Bu fp32 swz [2][16KB] ea.
// Loop: vmcnt(6) [stage(kt) done, stage(kt+1) in flight] -> bar -> comp ->
// bar -> stage(kt+2). Loads span ~2 iterations; NO vmcnt(0) until last iter;
// NO sched_barrier (m141). 6 gload_lds per wave per stage.
__global__ __launch_bounds__(512, 2) void gate_up_kernel(
    const _Float16* __restrict__ xb, const float* __restrict__ wg,
    const float* __restrict__ wu, const int* __restrict__ counts,
    const int* __restrict__ lists, _Float16* __restrict__ hbuf) {
  extern __shared__ char lds[];
  // A [2][16384] @0 ; Bg [2][16384] @32768 ; Bu [2][16384] @65536
  const int e = blockIdx.z;
  const int ne = counts[e];
  const int row0 = blockIdx.y * 256;
  if (row0 >= ne) return;
  const int col0 = blockIdx.x * 128;
  const int tid = threadIdx.x;
  const int lane = tid & 63;
  const int w = tid >> 6;
  const int wr = w >> 1, wc = w & 1;

  // ---- A sources: wave w stages m-blocks 2w, 2w+1 (frag-linear)
  const int* lst = lists + e * T_TOK;
  const _Float16* asrc[2];
#pragma unroll
  for (int i = 0; i < 2; ++i) {
    int r = row0 + (2 * w + i) * 16 + (lane & 15);
    int tok = lst[min(r, ne - 1)];
    asrc[i] = xb + (size_t)tok * H_DIM + (lane >> 4) * 8;
  }
  // ---- B sources: per matrix 2 instr/wave; instr i covers c-rows (w*2+i)*8+(l>>3)
  const float* bgs[2];
  const float* bus[2];
#pragma unroll
  for (int i = 0; i < 2; ++i) {
    int tr = (w * 2 + i) * 8 + (lane >> 3);
    int ls = (lane & 7) ^ (tr & 7);              // source pre-swizzle (16B chunks)
    bgs[i] = wg + ((size_t)e * I_DIM + col0 + tr) * H_DIM + ls * 4;
    bus[i] = wu + ((size_t)e * I_DIM + col0 + tr) * H_DIM + ls * 4;
  }

  f32x4 accg[4][4], accu[4][4];
  const f32x4 zz = {0.f, 0.f, 0.f, 0.f};
#pragma unroll
  for (int m = 0; m < 4; ++m)
#pragma unroll
    for (int n = 0; n < 4; ++n) { accg[m][n] = zz; accu[m][n] = zz; }

  auto stage = [&](int kt, int buf) {   // 6 pure-async instr per wave
    const int k0 = kt * 32;
#pragma unroll
    for (int i = 0; i < 2; ++i)
      gload_lds16(asrc[i] + k0, lds + buf * 16384 + (2 * w + i) * 1024);
#pragma unroll
    for (int i = 0; i < 2; ++i) {
      gload_lds16(bgs[i] + k0, lds + 32768 + buf * 16384 + (w * 2 + i) * 1024);
      gload_lds16(bus[i] + k0, lds + 65536 + buf * 16384 + (w * 2 + i) * 1024);
    }
  };

  auto comp = [&](int buf) {
    const char* Ab = lds + buf * 16384;
    const char* Gb = lds + 32768 + buf * 16384;
    const char* Ub = lds + 65536 + buf * 16384;
    f16x8 afr[4];
#pragma unroll
    for (int m = 0; m < 4; ++m)
      afr[m] = *(const f16x8*)(Ab + (wr * 4 + m) * 1024 + lane * 16);
    const int s0 = (lane >> 4) * 2;
#pragma unroll
    for (int n = 0; n < 4; ++n) {
      int c = wc * 64 + n * 16 + (lane & 15);
      int p0 = s0 ^ (c & 7);
      int p1 = (s0 + 1) ^ (c & 7);
      f16x8 bg = cvt8(*(const f32x4*)(Gb + c * 128 + p0 * 16),
                      *(const f32x4*)(Gb + c * 128 + p1 * 16));
      f16x8 bu = cvt8(*(const f32x4*)(Ub + c * 128 + p0 * 16),
                      *(const f32x4*)(Ub + c * 128 + p1 * 16));
#pragma unroll
      for (int m = 0; m < 4; ++m) {
        accg[m][n] = __builtin_amdgcn_mfma_f32_16x16x32_f16(afr[m], bg, accg[m][n], 0, 0, 0);
        accu[m][n] = __builtin_amdgcn_mfma_f32_16x16x32_f16(afr[m], bu, accu[m][n], 0, 0, 0);
      }
    }
  };

  const int NK = H_DIM / 32;   // 64
  stage(0, 0);
  stage(1, 1);
  for (int kt = 0; kt < NK; ++kt) {
    // retire stage(kt); stage(kt+1)'s 6 loads stay in flight across barrier
    if (kt < NK - 1) { asm volatile("s_waitcnt vmcnt(6)" ::: "memory"); }
    else             { asm volatile("s_waitcnt vmcnt(0)" ::: "memory"); }
    __builtin_amdgcn_s_barrier();
    asm volatile("" ::: "memory");      // keep comp's ds_reads below barrier
    comp(kt & 1);
    asm volatile("" ::: "memory");      // keep restage below comp
    __builtin_amdgcn_s_barrier();
    if (kt + 2 < NK) stage(kt + 2, kt & 1);
  }

  // epilogue: silu(g)*u -> fp16 h
  _Float16* hb = hbuf + (size_t)e * T_TOK * I_DIM;
#pragma unroll
  for (int m = 0; m < 4; ++m) {
#pragma unroll
    for (int j = 0; j < 4; ++j) {
      int r = row0 + wr * 64 + m * 16 + (lane >> 4) * 4 + j;
      if (r < ne) {
#pragma unroll
        for (int n = 0; n < 4; ++n) {
          int cc = col0 + wc * 64 + n * 16 + (lane & 15);
          float g = accg[m][n][j];
          float u = accu[m][n][j];
          float hv = (g / (1.f + __expf(-g))) * u;
          hb[(size_t)r * I_DIM + cc] = (_Float16)hv;
        }
      }
    }
  }
}

// ---------------- kernel 4: down GEMM, BK=64 all-async + scatter-add --------
// (unchanged from round 9 — L3-resident wd, measured near its floor)
__global__ __launch_bounds__(512) void down_kernel(
    const _Float16* __restrict__ hbuf, const float* __restrict__ wd,
    const int* __restrict__ counts, const int* __restrict__ lists,
    const float* __restrict__ coef, float* __restrict__ out) {
  extern __shared__ char lds[];
  // offsets: A [2][32768] @0 ; B [2][16384] @65536
  const int e = blockIdx.z;
  const int ne = counts[e];
  const int row0 = blockIdx.y * 256;
  if (row0 >= ne) return;
  const int col0 = blockIdx.x * 64;
  const int tid = threadIdx.x;
  const int lane = tid & 63;
  const int w = tid >> 6;
  const int wr = w >> 1, wc = w & 1;

  const _Float16* hb = hbuf + (size_t)e * T_TOK * I_DIM;
  const _Float16* asrc[4];
#pragma unroll
  for (int i = 0; i < 4; ++i) {
    int tr = (w * 4 + i) * 8 + (lane >> 3);
    int lchunk = (lane & 7) ^ (tr & 7);
    asrc[i] = hb + (size_t)(row0 + tr) * I_DIM + lchunk * 8;
  }
  const float* bds[2];
#pragma unroll
  for (int i = 0; i < 2; ++i) {
    int tr = (w * 2 + i) * 4 + (lane >> 4);
    int ls = (lane & 15) ^ ((tr & 7) << 1);
    bds[i] = wd + ((size_t)e * H_DIM + col0 + tr) * I_DIM + ls * 4;
  }

  f32x4 acc[4][2];
  const f32x4 zz = {0.f, 0.f, 0.f, 0.f};
#pragma unroll
  for (int m = 0; m < 4; ++m)
#pragma unroll
    for (int n = 0; n < 2; ++n) acc[m][n] = zz;

  auto stage = [&](int kt, int buf) {
    const int k0 = kt * 64;
#pragma unroll
    for (int i = 0; i < 4; ++i)
      gload_lds16(asrc[i] + k0, lds + buf * 32768 + (w * 4 + i) * 1024);
#pragma unroll
    for (int i = 0; i < 2; ++i)
      gload_lds16(bds[i] + k0, lds + 65536 + buf * 16384 + (w * 2 + i) * 1024);
  };

  auto comp = [&](int buf) {
    const char* Ab = lds + buf * 32768;
    const char* Bb = lds + 65536 + buf * 16384;
#pragma unroll
    for (int kk = 0; kk < 2; ++kk) {
      f16x8 afr[4], bf[2];
#pragma unroll
      for (int m = 0; m < 4; ++m) {
        int row = wr * 64 + m * 16 + (lane & 15);
        int pch = (kk * 4 + (lane >> 4)) ^ (row & 7);
        afr[m] = *(const f16x8*)(Ab + row * 128 + pch * 16);
      }
#pragma unroll
      for (int n = 0; n < 2; ++n) {
        int c = wc * 32 + n * 16 + (lane & 15);
        int s0 = kk * 8 + (lane >> 4) * 2;
        int p0 = s0 ^ ((c & 7) << 1);
        int p1 = (s0 + 1) ^ ((c & 7) << 1);
        bf[n] = cvt8(*(const f32x4*)(Bb + c * 256 + p0 * 16),
                     *(const f32x4*)(Bb + c * 256 + p1 * 16));
      }
#pragma unroll
      for (int m = 0; m < 4; ++m)
#pragma unroll
        for (int n = 0; n < 2; ++n)
          acc[m][n] = __builtin_amdgcn_mfma_f32_16x16x32_f16(afr[m], bf[n], acc[m][n], 0, 0, 0);
    }
  };

  const int NK = I_DIM / 64;   // 22
  stage(0, 0);
  for (int kt = 0; kt < NK; ++kt) {
    __syncthreads();
    if (kt + 1 < NK) stage(kt + 1, (kt + 1) & 1);
    comp(kt & 1);
  }

#pragma unroll
  for (int m = 0; m < 4; ++m) {
#pragma unroll
    for (int j = 0; j < 4; ++j) {
      int r = row0 + wr * 64 + m * 16 + (lane >> 4) * 4 + j;
      if (r < ne) {
        int tok = lists[e * T_TOK + r];
        float c = coef[tok * N_EXP + e];
#pragma unroll
        for (int n = 0; n < 2; ++n) {
          int cc = col0 + wc * 32 + n * 16 + (lane & 15);
          atomicAdd(&out[(size_t)tok * H_DIM + cc], acc[m][n][j] * c);
        }
      }
    }
  }
}

// ---------------- launch ----------------
extern "C" void kernel_launch(void* const* d_in, const int* in_sizes, int n_in,
                              void* d_out, int out_size, void* d_ws, size_t ws_size,
                              hipStream_t stream) {
  const float* x  = (const float*)d_in[0];
  const float* gw = (const float*)d_in[1];
  const float* cb = (const float*)d_in[2];
  const float* wg = (const float*)d_in[3];
  const float* wu = (const float*)d_in[4];
  const float* wd = (const float*)d_in[5];
  float* out = (float*)d_out;
  char* ws = (char*)d_ws;

  float* coef   = (float*)(ws);                    // 512*16*4 = 32768
  int*   counts = (int*)(ws + 32768);              // 64 B
  int*   lists  = (int*)(ws + 33024);              // 16*512*4 = 32768
  _Float16* xb  = (_Float16*)(ws + 66048);         // 512*2048*2 = 2 MiB
  _Float16* hbuf= (_Float16*)(ws + 66048 + 2097152 + 256); // 16*512*1408*2 = 23 MiB

  hipFuncSetAttribute((const void*)gate_up_kernel,
                      hipFuncAttributeMaxDynamicSharedMemorySize, 98304);
  hipFuncSetAttribute((const void*)down_kernel,
                      hipFuncAttributeMaxDynamicSharedMemorySize, 98304);

  hipMemsetAsync(d_out, 0, (size_t)out_size * sizeof(float), stream);

  route_kernel<<<T_TOK, 256, 0, stream>>>(x, gw, cb, coef, xb);
  build_lists_kernel<<<N_EXP, 512, 0, stream>>>(coef, counts, lists);
  gate_up_kernel<<<dim3(I_DIM / 128, 2, N_EXP), 512, 98304, stream>>>(xb, wg, wu, counts, lists, hbuf);
  down_kernel<<<dim3(H_DIM / 64, 2, N_EXP), 512, 98304, stream>>>(hbuf, wd, counts, lists, coef, out);
}